// Round 1
// baseline (372.032 us; speedup 1.0000x reference)
//
#include <hip/hip_runtime.h>

typedef __bf16 bf16;
typedef __bf16 bf16x8 __attribute__((ext_vector_type(8)));
typedef float  f32x4  __attribute__((ext_vector_type(4)));

#define DIM   1024
#define NH    16
#define NKV   4
#define HD    64
#define SLEN  264
#define BTOT  64            // B*T
#define MROWS (BTOT * SLEN) // 16896
#define NQKV  1536          // 1024 q + 256 k + 256 v
#define NZ    256
#define VPAD  288           // padded key dim of vt

// ---------------- async global->LDS (wave-uniform LDS base + lane*16; global src is per-lane) ----------------
__device__ __forceinline__ void gl_lds16(const bf16* g, bf16* l) {
    __builtin_amdgcn_global_load_lds((__attribute__((address_space(1))) void*)(g),
                                     (__attribute__((address_space(3))) void*)(l),
                                     16, 0, 0);
}

// ---------------- f32 -> bf16 converters ----------------
__global__ void cvt_f32_bf16(const float* __restrict__ src, bf16* __restrict__ dst, int n) {
    int i = (blockIdx.x * 256 + threadIdx.x) * 4;
    if (i < n) {
        float4 v = *(const float4*)(src + i);
        dst[i + 0] = (bf16)v.x; dst[i + 1] = (bf16)v.y;
        dst[i + 2] = (bf16)v.z; dst[i + 3] = (bf16)v.w;
    }
}

__global__ void cvt_wcat(const float* __restrict__ wq, const float* __restrict__ wk,
                         const float* __restrict__ wv, bf16* __restrict__ dst) {
    int i = (blockIdx.x * 256 + threadIdx.x) * 4;   // total 1536*1024
    const float* src; int off;
    if (i < 1024 * 1024)      { src = wq; off = i; }
    else if (i < 1280 * 1024) { src = wk; off = i - 1024 * 1024; }
    else                      { src = wv; off = i - 1280 * 1024; }
    float4 v = *(const float4*)(src + off);
    dst[i + 0] = (bf16)v.x; dst[i + 1] = (bf16)v.y;
    dst[i + 2] = (bf16)v.z; dst[i + 3] = (bf16)v.w;
}

// ---------------- RoPE cos/sin table: ctab[s][d] for d in 0..31 (period-32 in head dim) ----------------
__global__ void rope_tab_kernel(float2* __restrict__ ctab) {
    int i = blockIdx.x * 256 + threadIdx.x;   // 8192 = 256 x 32
    int s = i >> 5, d = i & 31;
    const float LN1 = 0.5756462732485115f;    // ln(10000)/16
    float pos = (d < 16) ? (float)(s >> 4) : (float)(s & 15);
    float ang = pos * expf(-(float)(d & 15) * LN1);
    float sn, cs; sincosf(ang, &sn, &cs);
    ctab[i] = make_float2(cs, sn);
}

// ================= 256x256 8-phase GEMM core (T2+T3+T4+T5) =================
// BM=BN=256, BK=64, 512 threads = 8 waves (2M x 4N), per-wave C = 2 x (64x64).
// Phase = (a = M-half of tile, ks = K-half). A halves split along M (contiguous
// 128x64 for global_load_lds); B halves split along K, stored as separate
// [256][32] sub-buffers (so each stays gl_lds-contiguous). Each of the 8 LDS
// half-buffers is its OWN __shared__ array: the compiler's per-object alias
// analysis then emits counted vmcnt waits (>= true outstanding = free) instead
// of vmcnt(0) drains before ds_reads.
// Per phase: 8 ds_read_b128 + 1 half-tile stage (2 gl_lds16) + barrier +
// setprio(1) + 16 MFMA + setprio(0) + barrier. vmcnt(4) only at phases 4/8
// (2 half-tiles in flight) — never vmcnt(0) in the main loop.
// Stage schedule (iteration it computes tiles 2it (buf0) / 2it+1 (buf1)):
//   ph1: A11<-t1  ph2: B11<-t1  ph3: A00<-t2  ph4: B00<-t2 +GATE
//   ph5: A01<-t2  ph6: B01<-t2  ph7: A10<-t3  ph8: B10<-t3 +GATE
// Each stage targets a half whose last read finished >=1 phase earlier
// (write-after-read safe via the end-of-phase barrier), and lands >=2 phases
// before its first read (enforced by the vmcnt(4) gates). Last iteration's
// t2/t3 clamp to 15 = dummy re-stages of the hot tile (L2-resident, C2-safe).

#define GATE4  asm volatile("s_waitcnt vmcnt(4)" ::: "memory")
#define NOGATE do {} while (0)

#define STAGE_A(DST, H, KT) do {                                                       \
    gl_lds16(Ag + (size_t)((H) * 128 + ars[0]) * DIM + (KT) * 64 + acs[0] * 8,         \
             (DST) + (wid * 64) * 8);                                                  \
    gl_lds16(Ag + (size_t)((H) * 128 + ars[1]) * DIM + (KT) * 64 + acs[1] * 8,         \
             (DST) + (512 + wid * 64) * 8);                                            \
} while (0)

#define STAGE_B(DST, KS, KT) do {                                                      \
    gl_lds16(Bg + (size_t)brs[0] * DIM + (KT) * 64 + (KS) * 32 + bcs[0] * 8,           \
             (DST) + (wid * 64) * 8);                                                  \
    gl_lds16(Bg + (size_t)brs[1] * DIM + (KT) * 64 + (KS) * 32 + bcs[1] * 8,           \
             (DST) + (512 + wid * 64) * 8);                                            \
} while (0)

#define PHASE(AARR, BARR, AA, KS, STAGE_STMT, GATE_STMT) do {                          \
    const bf16* Ab_ = (AARR) + aRdBase + axor[KS];                                     \
    const bf16* Bb_ = (BARR) + bRdBase + bxorv;                                        \
    bf16x8 af_[4], bf_[4];                                                             \
    _Pragma("unroll")                                                                  \
    for (int i_ = 0; i_ < 4; i_++) af_[i_] = *(const bf16x8*)(Ab_ + i_ * 1024);        \
    _Pragma("unroll")                                                                  \
    for (int n_ = 0; n_ < 4; n_++) bf_[n_] = *(const bf16x8*)(Bb_ + n_ * 512);         \
    STAGE_STMT;                                                                        \
    GATE_STMT;                                                                         \
    asm volatile("s_barrier" ::: "memory");                                            \
    __builtin_amdgcn_s_setprio(1);                                                     \
    _Pragma("unroll")                                                                  \
    for (int i_ = 0; i_ < 4; i_++)                                                     \
        _Pragma("unroll")                                                              \
        for (int n_ = 0; n_ < 4; n_++)                                                 \
            acc[AA][i_][n_] = __builtin_amdgcn_mfma_f32_16x16x32_bf16(                 \
                af_[i_], bf_[n_], acc[AA][i_][n_], 0, 0, 0);                           \
    __builtin_amdgcn_s_setprio(0);                                                     \
    asm volatile("s_barrier" ::: "memory");                                            \
} while (0)

__device__ __forceinline__ void gemm256_core(const bf16* __restrict__ Ag,
                                             const bf16* __restrict__ Bg,
                                             f32x4 (&acc)[2][4][4]) {
    // 8 separate half-buffers: A{buf}{Mhalf} 128x64, B{buf}{Khalf} 256x32. 128 KiB.
    __shared__ __align__(16) bf16 A00[128 * 64], A01[128 * 64], A10[128 * 64], A11[128 * 64];
    __shared__ __align__(16) bf16 B00[256 * 32], B01[256 * 32], B10[256 * 32], B11[256 * 32];

    const int tid  = threadIdx.x;
    const int wid  = tid >> 6, lane = tid & 63;
    const int quad = lane >> 4, r16 = lane & 15;
    const int wm = wid & 1, wn = wid >> 1;

    // staging source (row, chunk) per call: linear LDS slot s -> row, phys chunk;
    // source holds the inverse-swizzled logical chunk so swizzled reads see it.
    int ars[2], acs[2], brs[2], bcs[2];
#pragma unroll
    for (int k = 0; k < 2; k++) {
        int s = k * 512 + tid;
        ars[k] = s >> 3; acs[k] = (s & 7) ^ (ars[k] & 7);   // A: 8 chunks/row (64 cols)
        brs[k] = s >> 2; bcs[k] = (s & 3) ^ (brs[k] & 3);   // B: 4 chunks/row (32 cols)
    }
    const int aRdBase = (wm * 64 + r16) * 64;
    const int bRdBase = (wn * 64 + r16) * 32;
    const int axor[2] = { (quad ^ (r16 & 7)) * 8, ((4 + quad) ^ (r16 & 7)) * 8 };
    const int bxorv   = (quad ^ (r16 & 3)) * 8;

    // prologue: tile0 complete (8 loads) + tile1 A-h0/B-k0 (4 loads)
    STAGE_A(A00, 0, 0); STAGE_A(A01, 1, 0);
    STAGE_B(B00, 0, 0); STAGE_B(B01, 1, 0);
    STAGE_A(A10, 0, 1); STAGE_B(B10, 0, 1);
    GATE4;                                  // tile0 landed; tile1 halves may fly
    asm volatile("s_barrier" ::: "memory");

#pragma unroll 1
    for (int it = 0; it < 8; ++it) {        // 2 K-tiles / iter, NT = 16
        const int t1 = 2 * it + 1;
        int t2 = 2 * it + 2; if (t2 > 15) t2 = 15;
        int t3 = 2 * it + 3; if (t3 > 15) t3 = 15;
        PHASE(A00, B00, 0, 0, STAGE_A(A11, 1, t1), NOGATE);
        PHASE(A00, B01, 0, 1, STAGE_B(B11, 1, t1), NOGATE);
        PHASE(A01, B00, 1, 0, STAGE_A(A00, 0, t2), NOGATE);
        PHASE(A01, B01, 1, 1, STAGE_B(B00, 0, t2), GATE4);   // tile 2it+1 landed
        PHASE(A10, B10, 0, 0, STAGE_A(A01, 1, t2), NOGATE);
        PHASE(A10, B11, 0, 1, STAGE_B(B01, 1, t2), NOGATE);
        PHASE(A11, B10, 1, 0, STAGE_A(A10, 0, t3), NOGATE);
        PHASE(A11, B11, 1, 1, STAGE_B(B10, 0, t3), GATE4);   // tile 2it+2 landed
    }
}

// bijective XCD-chunked block swizzle (m204): contiguous wg-chunks per XCD
__device__ __forceinline__ int xcd_swizzle(int orig, int nwg) {
    int q = nwg >> 3, r = nwg & 7;
    int xcd = orig & 7, lid = orig >> 3;
    return (xcd < r ? xcd * (q + 1) : r * (q + 1) + (xcd - r) * q) + lid;
}

// ---------------- QKV GEMM with fused QKNorm + partial 2D-RoPE epilogue ----------------
// C[M,1536] = A[M,1024] @ W[1536,1024]^T. Each wave's 64 cols == one head
// (B K-split halves keep 64 contiguous N-cols per wave).
__global__ __launch_bounds__(512) void gemm_qkv(const bf16* __restrict__ A,
                                                const bf16* __restrict__ Bw,
                                                bf16* __restrict__ out,
                                                const float* __restrict__ qw,
                                                const float* __restrict__ kw,
                                                const float2* __restrict__ ctab) {
    const int nwg = (MROWS / 256) * (NQKV / 256);   // 396
    int wg = xcd_swizzle(blockIdx.x, nwg);
    const int bm = wg / 6, bn = wg - bm * 6;

    f32x4 acc[2][4][4];
#pragma unroll
    for (int a = 0; a < 2; a++)
#pragma unroll
        for (int i = 0; i < 4; i++)
#pragma unroll
            for (int n = 0; n < 4; n++) acc[a][i][n] = (f32x4){0.f, 0.f, 0.f, 0.f};

    gemm256_core(A + (size_t)bm * 256 * DIM, Bw + (size_t)bn * 256 * DIM, acc);

    const int tid  = threadIdx.x;
    const int wid  = tid >> 6, lane = tid & 63;
    const int quad = lane >> 4, r16 = lane & 15;
    const int wm = wid & 1, wn = wid >> 1;
    const int colbase = bn * 256 + wn * 64;          // 64-aligned -> one head per wave
    const int rowb    = bm * 256 + wm * 64;

    if (bn < 5) {
        const float* w = (bn < 4) ? qw : kw;
        float wreg[4];
#pragma unroll
        for (int n = 0; n < 4; n++) wreg[n] = w[n * 16 + r16];
#pragma unroll
        for (int a = 0; a < 2; a++)
#pragma unroll
            for (int i = 0; i < 4; i++)
#pragma unroll
                for (int r = 0; r < 4; r++) {
                    float ss = 0.f;
#pragma unroll
                    for (int n = 0; n < 4; n++) ss += acc[a][i][n][r] * acc[a][i][n][r];
                    ss += __shfl_xor(ss, 1, 64);
                    ss += __shfl_xor(ss, 2, 64);
                    ss += __shfl_xor(ss, 4, 64);
                    ss += __shfl_xor(ss, 8, 64);
                    float rms = rsqrtf(ss * (1.f / 64.f) + 1e-6f);
                    float xv[4];
#pragma unroll
                    for (int n = 0; n < 4; n++) xv[n] = acc[a][i][n][r] * rms * wreg[n];
                    int gm = rowb + a * 128 + i * 16 + quad * 4 + r;
                    int s = gm % SLEN;
                    if (s < NZ) {   // partial 2D RoPE; pairs (n, n+2) are lane-local
                        float2 cs0 = ctab[s * 32 + r16];
                        float2 cs1 = ctab[s * 32 + 16 + r16];
                        float a0 = xv[0] * cs0.x - xv[2] * cs0.y;
                        float a2 = xv[2] * cs0.x + xv[0] * cs0.y;
                        float a1 = xv[1] * cs1.x - xv[3] * cs1.y;
                        float a3 = xv[3] * cs1.x + xv[1] * cs1.y;
                        xv[0] = a0; xv[1] = a1; xv[2] = a2; xv[3] = a3;
                    }
                    size_t rowoff = (size_t)gm * NQKV + colbase + r16;
#pragma unroll
                    for (int n = 0; n < 4; n++) out[rowoff + n * 16] = (bf16)xv[n];
                }
    } else {
#pragma unroll
        for (int a = 0; a < 2; a++)
#pragma unroll
            for (int i = 0; i < 4; i++)
#pragma unroll
                for (int r = 0; r < 4; r++) {
                    int gm = rowb + a * 128 + i * 16 + quad * 4 + r;
                    size_t rowoff = (size_t)gm * NQKV + colbase + r16;
#pragma unroll
                    for (int n = 0; n < 4; n++) out[rowoff + n * 16] = (bf16)acc[a][i][n][r];
                }
    }
}

// ---------------- O-projection GEMM: C[M,1024]=A@B^T, f32 out ----------------
__global__ __launch_bounds__(512) void gemm_bt(const bf16* __restrict__ A,
                                               const bf16* __restrict__ Bw,
                                               float* __restrict__ Cout) {
    const int nwg = (MROWS / 256) * (DIM / 256);    // 264
    int wg = xcd_swizzle(blockIdx.x, nwg);
    const int bm = wg / 4, bn = wg - bm * 4;

    f32x4 acc[2][4][4];
#pragma unroll
    for (int a = 0; a < 2; a++)
#pragma unroll
        for (int i = 0; i < 4; i++)
#pragma unroll
            for (int n = 0; n < 4; n++) acc[a][i][n] = (f32x4){0.f, 0.f, 0.f, 0.f};

    gemm256_core(A + (size_t)bm * 256 * DIM, Bw + (size_t)bn * 256 * DIM, acc);

    const int tid  = threadIdx.x;
    const int wid  = tid >> 6, lane = tid & 63;
    const int quad = lane >> 4, r16 = lane & 15;
    const int wm = wid & 1, wn = wid >> 1;
    const int colbase = bn * 256 + wn * 64;
    const int rowb    = bm * 256 + wm * 64;
#pragma unroll
    for (int a = 0; a < 2; a++)
#pragma unroll
        for (int i = 0; i < 4; i++)
#pragma unroll
            for (int r = 0; r < 4; r++) {
                int gm = rowb + a * 128 + i * 16 + quad * 4 + r;
                size_t rowoff = (size_t)gm * DIM + colbase + r16;
#pragma unroll
                for (int n = 0; n < 4; n++) Cout[rowoff + n * 16] = acc[a][i][n][r];
            }
}

// ---------------- V transpose: qkv V region -> vt[(bt,kv)][d][key], zero-padded to 288 keys ----------------
__global__ __launch_bounds__(256) void vtrans_kernel(const bf16* __restrict__ qkv,
                                                     bf16* __restrict__ vt) {
    __shared__ bf16 Ls[64 * 272];
    const int tid = threadIdx.x;
    const int b = blockIdx.x, bt = b >> 2, kv = b & 3;
    const int part = tid >> 5;      // 0..7 (dim octet)
    const int rr   = tid & 31;      // row within pass
#pragma unroll
    for (int pass = 0; pass < 9; ++pass) {
        int row = pass * 32 + rr;
        if (row < SLEN) {
            bf16x8 v = *(const bf16x8*)(qkv + (size_t)(bt * SLEN + row) * NQKV + 1280 + kv * 64 + part * 8);
#pragma unroll
            for (int j = 0; j < 8; j++) Ls[(part * 8 + j) * 272 + row] = v[j];
        }
    }
    __syncthreads();
    const int d = tid >> 2, seg = tid & 3;
    size_t obase = ((size_t)b * 64 + d) * VPAD;
#pragma unroll
    for (int m = 0; m < 9; ++m) {
        int col = seg * 72 + m * 8;
        bf16x8 o;
#pragma unroll
        for (int j = 0; j < 8; j++) {
            int s = col + j;
            o[j] = (s < SLEN) ? Ls[d * 272 + s] : (bf16)0.f;
        }
        *(bf16x8*)(vt + obase + col) = o;
    }
}

// ---------------- attention v4: one wave per (32-row qtile-pair, head, bt) ----------------
// K prefetched one chunk ahead; softcap via odd-poly tanh (|z|<=0.16) + single exp2.
__global__ __launch_bounds__(256) void attn_kernel(const bf16* __restrict__ qkv,
                                                   const bf16* __restrict__ vt,
                                                   bf16* __restrict__ aout) {
    const int PLD = 40;
    __shared__ __align__(16) bf16 Pb[4][2][16 * PLD];   // per-wave, per-qtile P buffers

    const int tid = threadIdx.x;
    const int wid = tid >> 6, lane = tid & 63;
    const int quad = lane >> 4, r16 = lane & 15;
    const int qp = blockIdx.x;           // 0..8 (9 pairs of 16-row tiles = 288 rows)
    const int kv = blockIdx.y, bt = blockIdx.z;
    const int h = kv * 4 + wid;

    // Q A-fragments for two 16-row tiles
    bf16x8 qa[2][2];
#pragma unroll
    for (int qi = 0; qi < 2; qi++) {
        int q0 = qp * 32 + qi * 16 + r16;
        int qcl = q0 < SLEN ? q0 : SLEN - 1;
        const bf16* qb = qkv + (size_t)(bt * SLEN + qcl) * NQKV + h * HD + quad * 8;
        qa[qi][0] = *(const bf16x8*)qb;
        qa[qi][1] = *(const bf16x8*)(qb + 32);
    }

    f32x4 oacc[2][4];
    float lsum[2][4];
#pragma unroll
    for (int qi = 0; qi < 2; qi++)
#pragma unroll
        for (int i = 0; i < 4; i++) { oacc[qi][i] = (f32x4){0.f, 0.f, 0.f, 0.f}; lsum[qi][i] = 0.f; }

    const bf16* kbase = qkv + (size_t)bt * SLEN * NQKV + 1024 + kv * HD + quad * 8;
    const bf16* vbase = vt + (size_t)(bt * 4 + kv) * HD * VPAD;

    bf16x8 nk[2][2];
#pragma unroll
    for (int kt = 0; kt < 2; kt++) {
        int key = kt * 16 + r16;
        const bf16* kp = kbase + (size_t)key * NQKV;
        nk[kt][0] = *(const bf16x8*)kp;
        nk[kt][1] = *(const bf16x8*)(kp + 32);
    }

    for (int c = 0; c < 9; ++c) {
        bf16x8 ck[2][2];
#pragma unroll
        for (int kt = 0; kt < 2; kt++) { ck[kt][0] = nk[kt][0]; ck[kt][1] = nk[kt][1]; }
        if (c < 8) {   // prefetch next chunk's K
#pragma unroll
            for (int kt = 0; kt < 2; kt++) {
                int key = (c + 1) * 32 + kt * 16 + r16;
                int kc = key < SLEN ? key : SLEN - 1;
                const bf16* kp = kbase + (size_t)kc * NQKV;
                nk[kt][0] = *(const bf16x8*)kp;
                nk[kt][1] = *(const bf16x8*)(kp + 32);
            }
        }
        // V B-fragments (coalesced from vt; covered by QK+softcap latency)
        bf16x8 cv[4];
#pragma unroll
        for (int dt = 0; dt < 4; ++dt)
            cv[dt] = *(const bf16x8*)(vbase + (size_t)(dt * 16 + r16) * VPAD + c * 32 + quad * 8);

        // QK^T
        f32x4 s[2][2];
#pragma unroll
        for (int qi = 0; qi < 2; qi++)
#pragma unroll
            for (int kt = 0; kt < 2; kt++) {
                f32x4 t = (f32x4){0.f, 0.f, 0.f, 0.f};
                t = __builtin_amdgcn_mfma_f32_16x16x32_bf16(qa[qi][0], ck[kt][0], t, 0, 0, 0);
                t = __builtin_amdgcn_mfma_f32_16x16x32_bf16(qa[qi][1], ck[kt][1], t, 0, 0, 0);
                s[qi][kt] = t;
            }

        // softcap: p = exp(50*tanh(sc/400))  [|z|<=0.16 -> 5th-order odd poly, err<2e-7]
#pragma unroll
        for (int qi = 0; qi < 2; qi++) {
            bf16* Pw = &Pb[wid][qi][0];
#pragma unroll
            for (int kt = 0; kt < 2; kt++)
#pragma unroll
                for (int r = 0; r < 4; ++r) {
                    int key = c * 32 + kt * 16 + r16;
                    float sc = s[qi][kt][r];
                    float z = sc * 0.0025f;                       // sc*SCALE/50
                    float z2 = z * z;
                    float poly = fmaf(z2, fmaf(z2, 0.133333333f, -0.333333333f), 1.f);
                    float p = exp2f(sc * 0.18033688f * poly);     // 50*log2e*z*poly
                    p = (key < SLEN) ? p : 0.f;
                    bf16 pb = (bf16)p;
                    lsum[qi][r] += (float)pb;
                    Pw[(quad * 4 + r) * PLD + kt * 16 + r16] = pb;
                }
            // C-layout -> A-layout repack through per-wave LDS (wave-coherent, no barrier)
            bf16x8 pa = *(const bf16x8*)&Pw[r16 * PLD + quad * 8];
#pragma unroll
            for (int dt = 0; dt < 4; ++dt)
                oacc[qi][dt] = __builtin_amdgcn_mfma_f32_16x16x32_bf16(pa, cv[dt], oacc[qi][dt], 0, 0, 0);
        }
    }

    // finalize: reduce l across the 16 key-lanes, divide, store
#pragma unroll
    for (int qi = 0; qi < 2; qi++)
#pragma unroll
        for (int r = 0; r < 4; ++r) {
            float l = lsum[qi][r];
            l += __shfl_xor(l, 1, 64);
            l += __shfl_xor(l, 2, 64);
            l += __shfl_xor(l, 4, 64);
            l += __shfl_xor(l, 8, 64);
            float inv = 1.f / l;
            int q = qp * 32 + qi * 16 + quad * 4 + r;
            if (q < SLEN) {
                size_t base = (size_t)(bt * SLEN + q) * (NH * HD) + h * HD;
#pragma unroll
                for (int dt = 0; dt < 4; ++dt)
                    aout[base + dt * 16 + r16] = (bf16)(oacc[qi][dt][r] * inv);
            }
        }
}

// ---------------- launcher ----------------
extern "C" void kernel_launch(void* const* d_in, const int* in_sizes, int n_in,
                              void* d_out, int out_size, void* d_ws, size_t ws_size,
                              hipStream_t stream) {
    const float* x   = (const float*)d_in[0];
    const float* wq  = (const float*)d_in[1];
    const float* wk  = (const float*)d_in[2];
    const float* wv  = (const float*)d_in[3];
    const float* wo  = (const float*)d_in[4];
    const float* qnw = (const float*)d_in[5];
    const float* knw = (const float*)d_in[6];

    bf16* xbf  = (bf16*)d_ws;                        // 16896x1024 (reused as aout)
    bf16* wcat = xbf  + (size_t)MROWS * DIM;         // 1536x1024  [wq;wk;wv]
    bf16* wobf = wcat + (size_t)NQKV * DIM;          // 1024x1024
    bf16* qkv  = wobf + (size_t)DIM * DIM;           // 16896x1536
    bf16* vt   = qkv  + (size_t)MROWS * NQKV;        // 256x64x288
    float2* ctab = (float2*)(vt + (size_t)BTOT * NKV * HD * VPAD);  // 256x32
    bf16* aout = xbf;                                // xbf dead after gemm_qkv

    rope_tab_kernel<<<32, 256, 0, stream>>>(ctab);
    cvt_f32_bf16<<<(MROWS * DIM) / 1024, 256, 0, stream>>>(x, xbf, MROWS * DIM);
    cvt_wcat<<<(NQKV * DIM) / 1024, 256, 0, stream>>>(wq, wk, wv, wcat);
    cvt_f32_bf16<<<(DIM * DIM) / 1024, 256, 0, stream>>>(wo, wobf, DIM * DIM);

    gemm_qkv<<<(MROWS / 256) * (NQKV / 256), 512, 0, stream>>>(xbf, wcat, qkv, qnw, knw, ctab);
    vtrans_kernel<<<BTOT * NKV, 256, 0, stream>>>(qkv, vt);
    attn_kernel<<<dim3(9, NKV, BTOT), 256, 0, stream>>>(qkv, vt, aout);
    gemm_bt<<<(MROWS / 256) * (DIM / 256), 512, 0, stream>>>(aout, wobf, (float*)d_out);
}

// Round 2
// 344.839 us; speedup vs baseline: 1.0789x; 1.0789x over previous
//
#include <hip/hip_runtime.h>

typedef __bf16 bf16;
typedef __bf16 bf16x8 __attribute__((ext_vector_type(8)));
typedef float  f32x4  __attribute__((ext_vector_type(4)));

#define DIM   1024
#define NH    16
#define NKV   4
#define HD    64
#define SLEN  264
#define BTOT  64            // B*T
#define MROWS (BTOT * SLEN) // 16896
#define NQKV  1536          // 1024 q + 256 k + 256 v
#define NZ    256
#define VPAD  288           // padded key dim of vt

// ---------------- async global->LDS (wave-uniform LDS base + lane*16; global src is per-lane) ----------------
__device__ __forceinline__ void gl_lds16(const bf16* g, bf16* l) {
    __builtin_amdgcn_global_load_lds((__attribute__((address_space(1))) void*)(g),
                                     (__attribute__((address_space(3))) void*)(l),
                                     16, 0, 0);
}

// ---------------- f32 -> bf16 converters ----------------
__global__ void cvt_f32_bf16(const float* __restrict__ src, bf16* __restrict__ dst, int n) {
    int i = (blockIdx.x * 256 + threadIdx.x) * 4;
    if (i < n) {
        float4 v = *(const float4*)(src + i);
        dst[i + 0] = (bf16)v.x; dst[i + 1] = (bf16)v.y;
        dst[i + 2] = (bf16)v.z; dst[i + 3] = (bf16)v.w;
    }
}

__global__ void cvt_wcat(const float* __restrict__ wq, const float* __restrict__ wk,
                         const float* __restrict__ wv, bf16* __restrict__ dst) {
    int i = (blockIdx.x * 256 + threadIdx.x) * 4;   // total 1536*1024
    const float* src; int off;
    if (i < 1024 * 1024)      { src = wq; off = i; }
    else if (i < 1280 * 1024) { src = wk; off = i - 1024 * 1024; }
    else                      { src = wv; off = i - 1280 * 1024; }
    float4 v = *(const float4*)(src + off);
    dst[i + 0] = (bf16)v.x; dst[i + 1] = (bf16)v.y;
    dst[i + 2] = (bf16)v.z; dst[i + 3] = (bf16)v.w;
}

// ---------------- RoPE cos/sin table: ctab[s][d] for d in 0..31 (period-32 in head dim) ----------------
__global__ void rope_tab_kernel(float2* __restrict__ ctab) {
    int i = blockIdx.x * 256 + threadIdx.x;   // 8192 = 256 x 32
    int s = i >> 5, d = i & 31;
    const float LN1 = 0.5756462732485115f;    // ln(10000)/16
    float pos = (d < 16) ? (float)(s >> 4) : (float)(s & 15);
    float ang = pos * expf(-(float)(d & 15) * LN1);
    float sn, cs; sincosf(ang, &sn, &cs);
    ctab[i] = make_float2(cs, sn);
}

// bijective XCD-chunked block swizzle (m204): contiguous wg-chunks per XCD
__device__ __forceinline__ int xcd_swizzle(int orig, int nwg) {
    int q = nwg >> 3, r = nwg & 7;
    int xcd = orig & 7, lid = orig >> 3;
    return (xcd < r ? xcd * (q + 1) : r * (q + 1) + (xcd - r) * q) + lid;
}

// ================= 256x256 8-phase GEMM core (T2+T3+T4+T5) =================
// BM=BN=256, BK=64, 512 threads = 8 waves (2M x 4N), per-wave C = 2 x (64x64).
// ALL eight LDS buffers are [128][64] (128-byte rows -> row-invariant banks,
// conflict-free with the chunk-XOR swizzle; round-1's [256][32] B layout had
// 64B rows -> 4-way conflicts, 3.24M SQ_LDS_BANK_CONFLICT).
//   A{d}{a}: K-tile parity d, M-half a.   B{d}{h}: parity d, N-half h.
// Wave (wm = wid&1, wn = wid>>1) reads A[d][a] rows wm*64+.., B[d][wn>>1]
// rows (wn&1)*64+.. -- B half is wave-fixed.
// Phase = (a, ks). Per phase: 8 ds_read_b128 + stage of ONE 16KB buffer
// (2 gl_lds16) + [gate] + barrier + lgkmcnt(0) + setprio(1) + 16 MFMA +
// setprio(0) + barrier. vmcnt(2) gates only at ph4/ph8 -- never vmcnt(0).
// Stage schedule (iter it computes tiles t0=2it (d=0), t1=2it+1 (d=1);
// t2,t3 = next tiles, clamped at the end):
//   ph1: A11<-t1   ph2: B10<-t1   ph3: B11<-t1   ph4: A00<-t2 +GATE
//   ph5: A01<-t2   ph6: B00<-t2   ph7: B01<-t2   ph8: A10<-t3 +GATE
// Every stage targets a buffer whose last read ended >=1 barrier earlier;
// GATE@ph4 (vmcnt(2)) proves {prev-ph8, ph1..ph3} landed before ph5 reads;
// GATE@ph8 proves {ph4..ph7} landed before next ph1 reads.

#define GATE2  asm volatile("s_waitcnt vmcnt(2)" ::: "memory")
#define NOGATE do {} while (0)

// stage one [128][64] buffer from G at (row-block H*128, K-tile KT); the
// global source chunk is inverse-XOR'd so swizzled reads see logical data.
#define STAGE(DST, G, H, KT) do {                                              \
    gl_lds16((G) + (size_t)((H) * 128 + rs0) * DIM + (KT) * 64 + cs0 * 8,      \
             (DST) + wid * 512);                                               \
    gl_lds16((G) + (size_t)((H) * 128 + 64 + rs0) * DIM + (KT) * 64 + cs0 * 8, \
             (DST) + 4096 + wid * 512);                                        \
} while (0)

#define PHASE(Ad, Bd, AA, KS, STAGE_STMT, GATE_STMT) do {                      \
    bf16x8 af_[4], bf_[4];                                                     \
    _Pragma("unroll")                                                          \
    for (int i_ = 0; i_ < 4; i_++) {                                           \
        af_[i_] = *(const bf16x8*)((Ad) + aRdBase + i_ * 1024 + xorv[KS]);     \
        bf_[i_] = *(const bf16x8*)((Bd) + bRdBase + i_ * 1024 + xorv[KS]);     \
    }                                                                          \
    STAGE_STMT;                                                                \
    GATE_STMT;                                                                 \
    __builtin_amdgcn_s_barrier();                                              \
    asm volatile("s_waitcnt lgkmcnt(0)" ::: "memory");                         \
    __builtin_amdgcn_sched_barrier(0);                                         \
    __builtin_amdgcn_s_setprio(1);                                             \
    _Pragma("unroll")                                                          \
    for (int i_ = 0; i_ < 4; i_++)                                             \
        _Pragma("unroll")                                                      \
        for (int n_ = 0; n_ < 4; n_++)                                         \
            acc[AA][i_][n_] = __builtin_amdgcn_mfma_f32_16x16x32_bf16(         \
                af_[i_], bf_[n_], acc[AA][i_][n_], 0, 0, 0);                   \
    __builtin_amdgcn_s_setprio(0);                                             \
    __builtin_amdgcn_s_barrier();                                              \
} while (0)

__device__ __forceinline__ void gemm256_core(const bf16* __restrict__ Ag,
                                             const bf16* __restrict__ Bg,
                                             f32x4 (&acc)[2][4][4]) {
    __shared__ __align__(16) bf16 A00[128 * 64], A01[128 * 64], A10[128 * 64], A11[128 * 64];
    __shared__ __align__(16) bf16 B00[128 * 64], B01[128 * 64], B10[128 * 64], B11[128 * 64];

    const int tid  = threadIdx.x;
    const int wid  = tid >> 6, lane = tid & 63;
    const int quad = lane >> 4, r16 = lane & 15;
    const int wm = wid & 1, wn = wid >> 1;

    // staging source (row, chunk): LDS slot s=tid -> row tid>>3, phys chunk
    // tid&7; source holds the inverse-swizzled logical chunk. Second call is
    // row+64, same chunk (rs&7 unchanged).
    const int rs0 = tid >> 3;
    const int cs0 = (tid & 7) ^ (rs0 & 7);

    const int aRdBase = (wm * 64 + r16) * 64;
    const int bRdBase = ((wn & 1) * 64 + r16) * 64;
    const int xorv[2] = { (quad ^ (r16 & 7)) * 8, ((4 + quad) ^ (r16 & 7)) * 8 };

    const bf16* Bd0 = (wn & 2) ? B01 : B00;   // wave's N-half, parity 0
    const bf16* Bd1 = (wn & 2) ? B11 : B10;   // wave's N-half, parity 1

    // prologue: full tile0 + A-half0 of tile1 (5 units = 10 loads)
    STAGE(A00, Ag, 0, 0);
    STAGE(A01, Ag, 1, 0);
    STAGE(B00, Bg, 0, 0);
    STAGE(B01, Bg, 1, 0);
    STAGE(A10, Ag, 0, 1);
    GATE2;                                  // tile0 landed; A10<-t1 may fly
    __builtin_amdgcn_s_barrier();

#pragma unroll 1
    for (int it = 0; it < 8; ++it) {        // 2 K-tiles / iter, NT = 16
        const int t1 = 2 * it + 1;
        int t2 = 2 * it + 2; if (t2 > 15) t2 = 15;
        int t3 = 2 * it + 3; if (t3 > 15) t3 = 15;
        PHASE(A00, Bd0, 0, 0, STAGE(A11, Ag, 1, t1), NOGATE);
        PHASE(A00, Bd0, 0, 1, STAGE(B10, Bg, 0, t1), NOGATE);
        PHASE(A01, Bd0, 1, 0, STAGE(B11, Bg, 1, t1), NOGATE);
        PHASE(A01, Bd0, 1, 1, STAGE(A00, Ag, 0, t2), GATE2);   // t1 units landed
        PHASE(A10, Bd1, 0, 0, STAGE(A01, Ag, 1, t2), NOGATE);
        PHASE(A10, Bd1, 0, 1, STAGE(B00, Bg, 0, t2), NOGATE);
        PHASE(A11, Bd1, 1, 0, STAGE(B01, Bg, 1, t2), NOGATE);
        PHASE(A11, Bd1, 1, 1, STAGE(A10, Ag, 0, t3), GATE2);   // t2 units landed
    }
}

// ---------------- QKV GEMM with fused QKNorm + partial 2D-RoPE epilogue ----------------
// C[M,1536] = A[M,1024] @ W[1536,1024]^T. Each wave's 64 cols == one head.
__global__ __launch_bounds__(512) void gemm_qkv(const bf16* __restrict__ A,
                                                const bf16* __restrict__ Bw,
                                                bf16* __restrict__ out,
                                                const float* __restrict__ qw,
                                                const float* __restrict__ kw,
                                                const float2* __restrict__ ctab) {
    const int nwg = (MROWS / 256) * (NQKV / 256);   // 396
    int wg = xcd_swizzle(blockIdx.x, nwg);
    const int bm = wg / 6, bn = wg - bm * 6;

    f32x4 acc[2][4][4];
#pragma unroll
    for (int a = 0; a < 2; a++)
#pragma unroll
        for (int i = 0; i < 4; i++)
#pragma unroll
            for (int n = 0; n < 4; n++) acc[a][i][n] = (f32x4){0.f, 0.f, 0.f, 0.f};

    gemm256_core(A + (size_t)bm * 256 * DIM, Bw + (size_t)bn * 256 * DIM, acc);

    const int tid  = threadIdx.x;
    const int wid  = tid >> 6, lane = tid & 63;
    const int quad = lane >> 4, r16 = lane & 15;
    const int wm = wid & 1, wn = wid >> 1;
    const int colbase = bn * 256 + wn * 64;          // 64-aligned -> one head per wave
    const int rowb    = bm * 256 + wm * 64;

    if (bn < 5) {
        const float* w = (bn < 4) ? qw : kw;
        float wreg[4];
#pragma unroll
        for (int n = 0; n < 4; n++) wreg[n] = w[n * 16 + r16];
#pragma unroll
        for (int a = 0; a < 2; a++)
#pragma unroll
            for (int i = 0; i < 4; i++)
#pragma unroll
                for (int r = 0; r < 4; r++) {
                    float ss = 0.f;
#pragma unroll
                    for (int n = 0; n < 4; n++) ss += acc[a][i][n][r] * acc[a][i][n][r];
                    ss += __shfl_xor(ss, 1, 64);
                    ss += __shfl_xor(ss, 2, 64);
                    ss += __shfl_xor(ss, 4, 64);
                    ss += __shfl_xor(ss, 8, 64);
                    float rms = rsqrtf(ss * (1.f / 64.f) + 1e-6f);
                    float xv[4];
#pragma unroll
                    for (int n = 0; n < 4; n++) xv[n] = acc[a][i][n][r] * rms * wreg[n];
                    int gm = rowb + a * 128 + i * 16 + quad * 4 + r;
                    int s = gm % SLEN;
                    if (s < NZ) {   // partial 2D RoPE; pairs (n, n+2) are lane-local
                        float2 cs0 = ctab[s * 32 + r16];
                        float2 cs1 = ctab[s * 32 + 16 + r16];
                        float a0 = xv[0] * cs0.x - xv[2] * cs0.y;
                        float a2 = xv[2] * cs0.x + xv[0] * cs0.y;
                        float a1 = xv[1] * cs1.x - xv[3] * cs1.y;
                        float a3 = xv[3] * cs1.x + xv[1] * cs1.y;
                        xv[0] = a0; xv[1] = a1; xv[2] = a2; xv[3] = a3;
                    }
                    size_t rowoff = (size_t)gm * NQKV + colbase + r16;
#pragma unroll
                    for (int n = 0; n < 4; n++) out[rowoff + n * 16] = (bf16)xv[n];
                }
    } else {
#pragma unroll
        for (int a = 0; a < 2; a++)
#pragma unroll
            for (int i = 0; i < 4; i++)
#pragma unroll
                for (int r = 0; r < 4; r++) {
                    int gm = rowb + a * 128 + i * 16 + quad * 4 + r;
                    size_t rowoff = (size_t)gm * NQKV + colbase + r16;
#pragma unroll
                    for (int n = 0; n < 4; n++) out[rowoff + n * 16] = (bf16)acc[a][i][n][r];
                }
    }
}

// ================= 128x128 2-phase core for gemm_bt (3-4 blocks/CU, no tail) =================
#define GEMM_STAGE_PTRS(Mptr, tileRow, K, P)                                   \
    const bf16* P[4];                                                          \
    {                                                                          \
        _Pragma("unroll")                                                      \
        for (int k = 0; k < 4; k++) {                                          \
            int s = k * 256 + tid;                                             \
            int r = s >> 3, cp = s & 7;                                        \
            int c = cp ^ (r & 7);                                              \
            P[k] = (Mptr) + (size_t)((tileRow) + r) * (K) + c * 8;             \
        }                                                                      \
    }

__device__ __forceinline__ int swz(int row, int chunk) {   // LDS element offset
    return row * 64 + ((chunk ^ (row & 7)) * 8);
}

// ---------------- O-projection GEMM: C[M,1024]=A@B^T, f32 out, BK=64 core ----------------
__global__ __launch_bounds__(256) void gemm_bt(const bf16* __restrict__ A,
                                               const bf16* __restrict__ Bw,
                                               float* __restrict__ Cout) {
    __shared__ __align__(16) bf16 As[128 * 64];
    __shared__ __align__(16) bf16 Bs[128 * 64];
    const int tid  = threadIdx.x;
    const int wid  = tid >> 6, lane = tid & 63;
    const int quad = lane >> 4, r16 = lane & 15;
    const int bid = blockIdx.x;
    const int g = bid / 32, rr = bid - g * 32;
    const int bm = g * 4 + (rr & 3), bn = rr >> 2;
    const int wm = wid & 1, wn = wid >> 1;

    GEMM_STAGE_PTRS(A,  bm * 128, DIM, Ap)
    GEMM_STAGE_PTRS(Bw, bn * 128, DIM, Bp)

    f32x4 acc[4][4];
#pragma unroll
    for (int i = 0; i < 4; i++)
#pragma unroll
        for (int j = 0; j < 4; j++) acc[i][j] = (f32x4){0.f, 0.f, 0.f, 0.f};

    for (int k0 = 0; k0 < DIM; k0 += 64) {
        __syncthreads();
#pragma unroll
        for (int k = 0; k < 4; k++) {
            gl_lds16(Ap[k] + k0, As + (k * 256 + wid * 64) * 8);
            gl_lds16(Bp[k] + k0, Bs + (k * 256 + wid * 64) * 8);
        }
        __syncthreads();
#pragma unroll
        for (int ks = 0; ks < 2; ks++) {
            bf16x8 a[4], b[4];
#pragma unroll
            for (int i = 0; i < 4; i++) {
                a[i] = *(const bf16x8*)&As[swz(wm * 64 + i * 16 + r16, ks * 4 + quad)];
                b[i] = *(const bf16x8*)&Bs[swz(wn * 64 + i * 16 + r16, ks * 4 + quad)];
            }
#pragma unroll
            for (int i = 0; i < 4; i++)
#pragma unroll
                for (int j = 0; j < 4; j++)
                    acc[i][j] = __builtin_amdgcn_mfma_f32_16x16x32_bf16(a[i], b[j], acc[i][j], 0, 0, 0);
        }
    }

#pragma unroll
    for (int i = 0; i < 4; i++)
#pragma unroll
        for (int j = 0; j < 4; j++)
#pragma unroll
            for (int r = 0; r < 4; r++) {
                int gm = bm * 128 + wm * 64 + i * 16 + quad * 4 + r;
                int gn = bn * 128 + wn * 64 + j * 16 + r16;
                Cout[(size_t)gm * DIM + gn] = acc[i][j][r];
            }
}

// ---------------- V transpose: qkv V region -> vt[(bt,kv)][d][key], zero-padded to 288 keys ----------------
__global__ __launch_bounds__(256) void vtrans_kernel(const bf16* __restrict__ qkv,
                                                     bf16* __restrict__ vt) {
    __shared__ bf16 Ls[64 * 272];
    const int tid = threadIdx.x;
    const int b = blockIdx.x, bt = b >> 2, kv = b & 3;
    const int part = tid >> 5;      // 0..7 (dim octet)
    const int rr   = tid & 31;      // row within pass
#pragma unroll
    for (int pass = 0; pass < 9; ++pass) {
        int row = pass * 32 + rr;
        if (row < SLEN) {
            bf16x8 v = *(const bf16x8*)(qkv + (size_t)(bt * SLEN + row) * NQKV + 1280 + kv * 64 + part * 8);
#pragma unroll
            for (int j = 0; j < 8; j++) Ls[(part * 8 + j) * 272 + row] = v[j];
        }
    }
    __syncthreads();
    const int d = tid >> 2, seg = tid & 3;
    size_t obase = ((size_t)b * 64 + d) * VPAD;
#pragma unroll
    for (int m = 0; m < 9; ++m) {
        int col = seg * 72 + m * 8;
        bf16x8 o;
#pragma unroll
        for (int j = 0; j < 8; j++) {
            int s = col + j;
            o[j] = (s < SLEN) ? Ls[d * 272 + s] : (bf16)0.f;
        }
        *(bf16x8*)(vt + obase + col) = o;
    }
}

// ---------------- attention v4: one wave per (32-row qtile-pair, head, bt) ----------------
// K prefetched one chunk ahead; softcap via odd-poly tanh (|z|<=0.16) + single exp2.
__global__ __launch_bounds__(256) void attn_kernel(const bf16* __restrict__ qkv,
                                                   const bf16* __restrict__ vt,
                                                   bf16* __restrict__ aout) {
    const int PLD = 40;
    __shared__ __align__(16) bf16 Pb[4][2][16 * PLD];   // per-wave, per-qtile P buffers

    const int tid = threadIdx.x;
    const int wid = tid >> 6, lane = tid & 63;
    const int quad = lane >> 4, r16 = lane & 15;
    const int qp = blockIdx.x;           // 0..8 (9 pairs of 16-row tiles = 288 rows)
    const int kv = blockIdx.y, bt = blockIdx.z;
    const int h = kv * 4 + wid;

    // Q A-fragments for two 16-row tiles
    bf16x8 qa[2][2];
#pragma unroll
    for (int qi = 0; qi < 2; qi++) {
        int q0 = qp * 32 + qi * 16 + r16;
        int qcl = q0 < SLEN ? q0 : SLEN - 1;
        const bf16* qb = qkv + (size_t)(bt * SLEN + qcl) * NQKV + h * HD + quad * 8;
        qa[qi][0] = *(const bf16x8*)qb;
        qa[qi][1] = *(const bf16x8*)(qb + 32);
    }

    f32x4 oacc[2][4];
    float lsum[2][4];
#pragma unroll
    for (int qi = 0; qi < 2; qi++)
#pragma unroll
        for (int i = 0; i < 4; i++) { oacc[qi][i] = (f32x4){0.f, 0.f, 0.f, 0.f}; lsum[qi][i] = 0.f; }

    const bf16* kbase = qkv + (size_t)bt * SLEN * NQKV + 1024 + kv * HD + quad * 8;
    const bf16* vbase = vt + (size_t)(bt * 4 + kv) * HD * VPAD;

    bf16x8 nk[2][2];
#pragma unroll
    for (int kt = 0; kt < 2; kt++) {
        int key = kt * 16 + r16;
        const bf16* kp = kbase + (size_t)key * NQKV;
        nk[kt][0] = *(const bf16x8*)kp;
        nk[kt][1] = *(const bf16x8*)(kp + 32);
    }

    for (int c = 0; c < 9; ++c) {
        bf16x8 ck[2][2];
#pragma unroll
        for (int kt = 0; kt < 2; kt++) { ck[kt][0] = nk[kt][0]; ck[kt][1] = nk[kt][1]; }
        if (c < 8) {   // prefetch next chunk's K
#pragma unroll
            for (int kt = 0; kt < 2; kt++) {
                int key = (c + 1) * 32 + kt * 16 + r16;
                int kc = key < SLEN ? key : SLEN - 1;
                const bf16* kp = kbase + (size_t)kc * NQKV;
                nk[kt][0] = *(const bf16x8*)kp;
                nk[kt][1] = *(const bf16x8*)(kp + 32);
            }
        }
        // V B-fragments (coalesced from vt; covered by QK+softcap latency)
        bf16x8 cv[4];
#pragma unroll
        for (int dt = 0; dt < 4; ++dt)
            cv[dt] = *(const bf16x8*)(vbase + (size_t)(dt * 16 + r16) * VPAD + c * 32 + quad * 8);

        // QK^T
        f32x4 s[2][2];
#pragma unroll
        for (int qi = 0; qi < 2; qi++)
#pragma unroll
            for (int kt = 0; kt < 2; kt++) {
                f32x4 t = (f32x4){0.f, 0.f, 0.f, 0.f};
                t = __builtin_amdgcn_mfma_f32_16x16x32_bf16(qa[qi][0], ck[kt][0], t, 0, 0, 0);
                t = __builtin_amdgcn_mfma_f32_16x16x32_bf16(qa[qi][1], ck[kt][1], t, 0, 0, 0);
                s[qi][kt] = t;
            }

        // softcap: p = exp(50*tanh(sc/400))  [|z|<=0.16 -> 5th-order odd poly, err<2e-7]
#pragma unroll
        for (int qi = 0; qi < 2; qi++) {
            bf16* Pw = &Pb[wid][qi][0];
#pragma unroll
            for (int kt = 0; kt < 2; kt++)
#pragma unroll
                for (int r = 0; r < 4; ++r) {
                    int key = c * 32 + kt * 16 + r16;
                    float sc = s[qi][kt][r];
                    float z = sc * 0.0025f;                       // sc*SCALE/50
                    float z2 = z * z;
                    float poly = fmaf(z2, fmaf(z2, 0.133333333f, -0.333333333f), 1.f);
                    float p = exp2f(sc * 0.18033688f * poly);     // 50*log2e*z*poly
                    p = (key < SLEN) ? p : 0.f;
                    bf16 pb = (bf16)p;
                    lsum[qi][r] += (float)pb;
                    Pw[(quad * 4 + r) * PLD + kt * 16 + r16] = pb;
                }
            // C-layout -> A-layout repack through per-wave LDS (wave-coherent, no barrier)
            bf16x8 pa = *(const bf16x8*)&Pw[r16 * PLD + quad * 8];
#pragma unroll
            for (int dt = 0; dt < 4; ++dt)
                oacc[qi][dt] = __builtin_amdgcn_mfma_f32_16x16x32_bf16(pa, cv[dt], oacc[qi][dt], 0, 0, 0);
        }
    }

    // finalize: reduce l across the 16 key-lanes, divide, store
#pragma unroll
    for (int qi = 0; qi < 2; qi++)
#pragma unroll
        for (int r = 0; r < 4; ++r) {
            float l = lsum[qi][r];
            l += __shfl_xor(l, 1, 64);
            l += __shfl_xor(l, 2, 64);
            l += __shfl_xor(l, 4, 64);
            l += __shfl_xor(l, 8, 64);
            float inv = 1.f / l;
            int q = qp * 32 + qi * 16 + quad * 4 + r;
            if (q < SLEN) {
                size_t base = (size_t)(bt * SLEN + q) * (NH * HD) + h * HD;
#pragma unroll
                for (int dt = 0; dt < 4; ++dt)
                    aout[base + dt * 16 + r16] = (bf16)(oacc[qi][dt][r] * inv);
            }
        }
}

// ---------------- launcher ----------------
extern "C" void kernel_launch(void* const* d_in, const int* in_sizes, int n_in,
                              void* d_out, int out_size, void* d_ws, size_t ws_size,
                              hipStream_t stream) {
    const float* x   = (const float*)d_in[0];
    const float* wq  = (const float*)d_in[1];
    const float* wk  = (const float*)d_in[2];
    const float* wv  = (const float*)d_in[3];
    const float* wo  = (const float*)d_in[4];
    const float* qnw = (const float*)d_in[5];
    const float* knw = (const float*)d_in[6];

    bf16* xbf  = (bf16*)d_ws;                        // 16896x1024 (reused as aout)
    bf16* wcat = xbf  + (size_t)MROWS * DIM;         // 1536x1024  [wq;wk;wv]
    bf16* wobf = wcat + (size_t)NQKV * DIM;          // 1024x1024
    bf16* qkv  = wobf + (size_t)DIM * DIM;           // 16896x1536
    bf16* vt   = qkv  + (size_t)MROWS * NQKV;        // 256x64x288
    float2* ctab = (float2*)(vt + (size_t)BTOT * NKV * HD * VPAD);  // 256x32
    bf16* aout = xbf;                                // xbf dead after gemm_qkv

    rope_tab_kernel<<<32, 256, 0, stream>>>(ctab);
    cvt_f32_bf16<<<(MROWS * DIM) / 1024, 256, 0, stream>>>(x, xbf, MROWS * DIM);
    cvt_wcat<<<(NQKV * DIM) / 1024, 256, 0, stream>>>(wq, wk, wv, wcat);
    cvt_f32_bf16<<<(DIM * DIM) / 1024, 256, 0, stream>>>(wo, wobf, DIM * DIM);

    gemm_qkv<<<(MROWS / 256) * (NQKV / 256), 512, 0, stream>>>(xbf, wcat, qkv, qnw, knw, ctab);
    vtrans_kernel<<<BTOT * NKV, 256, 0, stream>>>(qkv, vt);
    attn_kernel<<<dim3(9, NKV, BTOT), 256, 0, stream>>>(qkv, vt, aout);
    gemm_bt<<<(MROWS / 128) * (DIM / 128), 256, 0, stream>>>(aout, wobf, (float*)d_out);
}